// Round 1
// baseline (1409.306 us; speedup 1.0000x reference)
//
#include <hip/hip_runtime.h>
#include <math.h>

#define Nn 100000
#define Ee 1600000
#define Mm (Ee + Nn)
#define Gg 256
#define EPSf 1e-5f

// ---------------- CSR build ----------------

__global__ void k_init(int* __restrict__ deg, int n) {
  int i = blockIdx.x * 256 + threadIdx.x;
  if (i < n) deg[i] = 1;  // self-loop counts as 1
}

__global__ void k_hist(const int* __restrict__ dst, int* __restrict__ deg, int e) {
  int i = blockIdx.x * 256 + threadIdx.x;
  if (i < e) atomicAdd(&deg[dst[i]], 1);
}

__global__ void k_scan1(const int* __restrict__ deg, int* __restrict__ rp,
                        int* __restrict__ blk, int n) {
  __shared__ int s[256];
  int b = blockIdx.x, t = threadIdx.x;
  int i0 = b * 1024 + t * 4;
  int v0 = (i0     < n) ? deg[i0]     : 0;
  int v1 = (i0 + 1 < n) ? deg[i0 + 1] : 0;
  int v2 = (i0 + 2 < n) ? deg[i0 + 2] : 0;
  int v3 = (i0 + 3 < n) ? deg[i0 + 3] : 0;
  int sum = v0 + v1 + v2 + v3;
  s[t] = sum; __syncthreads();
  for (int o = 1; o < 256; o <<= 1) {
    int u = (t >= o) ? s[t - o] : 0;
    __syncthreads();
    s[t] += u;
    __syncthreads();
  }
  int excl = s[t] - sum;
  if (i0     < n) rp[i0]     = excl;
  if (i0 + 1 < n) rp[i0 + 1] = excl + v0;
  if (i0 + 2 < n) rp[i0 + 2] = excl + v0 + v1;
  if (i0 + 3 < n) rp[i0 + 3] = excl + v0 + v1 + v2;
  if (t == 255) blk[b] = s[255];
}

__global__ void k_scan2(int* __restrict__ blk, int nblk, int* __restrict__ tot) {
  __shared__ int s[128];
  int t = threadIdx.x;
  int v = (t < nblk) ? blk[t] : 0;
  s[t] = v; __syncthreads();
  for (int o = 1; o < 128; o <<= 1) {
    int u = (t >= o) ? s[t - o] : 0;
    __syncthreads(); s[t] += u; __syncthreads();
  }
  if (t < nblk) blk[t] = s[t] - v;          // exclusive block prefix
  if (t == nblk - 1) tot[0] = s[t];         // row_ptr[N] = E+N
}

__global__ void k_scan3(int* __restrict__ rp, int* __restrict__ fill,
                        const int* __restrict__ blk, int n) {
  int b = blockIdx.x;
  int add = blk[b];
  int i0 = b * 1024 + threadIdx.x * 4;
  #pragma unroll
  for (int k = 0; k < 4; ++k) {
    int i = i0 + k;
    if (i < n) { int v = rp[i] + add; rp[i] = v; fill[i] = v; }
  }
}

__global__ void k_scatter(const int* __restrict__ src, const int* __restrict__ dst,
                          int* __restrict__ fill, int* __restrict__ csr, int e, int n) {
  int i = blockIdx.x * 256 + threadIdx.x;
  if (i >= e + n) return;
  int s, v;
  if (i < e) { s = src[i]; v = dst[i]; } else { s = v = i - e; }
  int p = atomicAdd(&fill[v], 1);
  csr[p] = s;
}

// ---------------- GEMM: H = X(N,128) @ W(128,128) ----------------
// W fully resident in 64 KB LDS; each thread computes 4 rows x 2 cols.
// X rows read via wave-uniform broadcast loads (L1-cached).

__global__ __launch_bounds__(256) void k_gemm(const float* __restrict__ X,
                                              const float* __restrict__ Wg,
                                              float* __restrict__ H, int n) {
  __shared__ float Wl[128 * 128];
  for (int i = threadIdx.x; i < 128 * 128; i += 256) Wl[i] = Wg[i];
  __syncthreads();
  int t = threadIdx.x;
  int c0 = (t & 63) * 2;      // col pair
  int rq = (t >> 6) * 4;      // row quad within 16-row group (per wave)
  int ngrp = (n + 15) >> 4;   // n == 100000 is a multiple of 16
  for (int grp = blockIdx.x; grp < ngrp; grp += gridDim.x) {
    int r0 = grp * 16 + rq;
    const float* xp = X + (size_t)r0 * 128;
    float a00 = 0, a01 = 0, a10 = 0, a11 = 0, a20 = 0, a21 = 0, a30 = 0, a31 = 0;
    #pragma unroll 4
    for (int k = 0; k < 128; ++k) {
      float2 w = *reinterpret_cast<const float2*>(&Wl[k * 128 + c0]);
      float xa = xp[k], xb = xp[128 + k], xc = xp[256 + k], xd = xp[384 + k];
      a00 += xa * w.x; a01 += xa * w.y;
      a10 += xb * w.x; a11 += xb * w.y;
      a20 += xc * w.x; a21 += xc * w.y;
      a30 += xd * w.x; a31 += xd * w.y;
    }
    *reinterpret_cast<float2*>(&H[(size_t)(r0 + 0) * 128 + c0]) = make_float2(a00, a01);
    *reinterpret_cast<float2*>(&H[(size_t)(r0 + 1) * 128 + c0]) = make_float2(a10, a11);
    *reinterpret_cast<float2*>(&H[(size_t)(r0 + 2) * 128 + c0]) = make_float2(a20, a21);
    *reinterpret_cast<float2*>(&H[(size_t)(r0 + 3) * 128 + c0]) = make_float2(a30, a31);
  }
}

// ---------------- per-node attention dots: es = H.asrc, ed = H.adst ----------------

__global__ __launch_bounds__(256) void k_dots(const float* __restrict__ H,
                                              const float* __restrict__ asrc,
                                              const float* __restrict__ adst,
                                              float* __restrict__ es, float* __restrict__ ed, int n) {
  int v = blockIdx.x * 4 + (threadIdx.x >> 6);
  if (v >= n) return;
  int lane = threadIdx.x & 63;
  float h0 = H[(size_t)v * 128 + lane];
  float h1 = H[(size_t)v * 128 + 64 + lane];
  float s = h0 * asrc[lane] + h1 * asrc[64 + lane];
  float d = h0 * adst[lane] + h1 * adst[64 + lane];
  #pragma unroll
  for (int o = 32; o; o >>= 1) { s += __shfl_xor(s, o); d += __shfl_xor(d, o); }
  if (lane == 0) { es[v] = s; ed[v] = d; }
}

// ---------------- aggregation: softmax-weighted neighbor sum, one wave per dst ----------------

__global__ __launch_bounds__(256) void k_agg(const float* __restrict__ H,
                                             const int* __restrict__ rp,
                                             const int* __restrict__ csr,
                                             const float* __restrict__ es,
                                             const float* __restrict__ ed,
                                             const float* __restrict__ bias,
                                             float* __restrict__ Xo, int n) {
  int v = blockIdx.x * 4 + (threadIdx.x >> 6);
  if (v >= n) return;
  int lane = threadIdx.x & 63;
  int r0 = rp[v], r1 = rp[v + 1];
  float edv = ed[v];
  float m = -3.0e38f;
  for (int j = r0 + lane; j < r1; j += 64) {
    float e = es[csr[j]] + edv;
    e = e > 0.f ? e : 0.2f * e;
    m = fmaxf(m, e);
  }
  #pragma unroll
  for (int o = 32; o; o >>= 1) m = fmaxf(m, __shfl_xor(m, o));
  float den = 0.f;
  for (int j = r0 + lane; j < r1; j += 64) {
    float e = es[csr[j]] + edv;
    e = e > 0.f ? e : 0.2f * e;
    den += __expf(e - m);
  }
  #pragma unroll
  for (int o = 32; o; o >>= 1) den += __shfl_xor(den, o);
  float inv = 1.f / den;
  float a0 = 0.f, a1 = 0.f;
  for (int j = r0; j < r1; ++j) {           // wave-uniform loop, coalesced H row loads
    int u = csr[j];
    float e = es[u] + edv;
    e = e > 0.f ? e : 0.2f * e;
    float pw = __expf(e - m);
    a0 += pw * H[(size_t)u * 128 + lane];
    a1 += pw * H[(size_t)u * 128 + 64 + lane];
  }
  Xo[(size_t)v * 128 + lane]      = fmaxf(a0 * inv + bias[lane], 0.f);
  Xo[(size_t)v * 128 + 64 + lane] = fmaxf(a1 * inv + bias[64 + lane], 0.f);
}

// ---------------- pooling (mean per graph, batch_ids sorted) + BN ----------------

__global__ void k_pool(const float* __restrict__ X, const int* __restrict__ batch,
                       const float* __restrict__ bn, float* __restrict__ xg, int n) {
  int g = blockIdx.x, t = threadIdx.x;
  int lo = 0, hi = n;
  while (lo < hi) { int mid = (lo + hi) >> 1; if (batch[mid] < g) lo = mid + 1; else hi = mid; }
  int s0 = lo;
  lo = s0; hi = n;
  while (lo < hi) { int mid = (lo + hi) >> 1; if (batch[mid] < g + 1) lo = mid + 1; else hi = mid; }
  int e0 = lo;
  float acc = 0.f;
  for (int i = s0; i < e0; ++i) acc += X[(size_t)i * 128 + t];
  float mean = (e0 > s0) ? acc / (float)(e0 - s0) : 0.f;
  float gm = bn[t], bt = bn[128 + t], mu = bn[256 + t], vr = bn[384 + t];
  xg[g * 128 + t] = (mean - mu) * gm * rsqrtf(vr + EPSf) + bt;
}

// ---------------- heads: fc1/bn, fc2/argmax, bn_comb/fc3a/fc3b masked ----------------

__global__ void k_heads(const float* __restrict__ xg, const float* __restrict__ gf,
                        const float* __restrict__ bn_t1, const float* __restrict__ bn_comb,
                        const float* __restrict__ fc1w, const float* __restrict__ fc1b,
                        const float* __restrict__ fc2w, const float* __restrict__ fc2b,
                        const float* __restrict__ fc3aw, const float* __restrict__ fc3ab,
                        const float* __restrict__ fc3bw, const float* __restrict__ fc3bb,
                        float* __restrict__ out) {
  int g = blockIdx.x;
  int lane = threadIdx.x;   // block of 64 = one wave
  __shared__ float xs[128];
  __shared__ float x3[133];
  __shared__ float o2[2];
  xs[lane] = xg[g * 128 + lane];
  xs[lane + 64] = xg[g * 128 + 64 + lane];
  __syncthreads();
  const float* gfg = &gf[g * 8];
  float lev = gfg[7];
  float nx0 = gfg[5], nx1 = gfg[6], nx2 = gfg[7];
  float wf1 = gfg[2], wf2 = gfg[1];
  // out1 : (x,lev) @ fc1 (129x10) -> relu -> BN(bn_t1)
  if (lane < 10) {
    float o = fc1b[lane];
    for (int k = 0; k < 128; ++k) o += xs[k] * fc1w[k * 10 + lane];
    o += lev * fc1w[128 * 10 + lane];
    o = fmaxf(o, 0.f);
    float gm = bn_t1[lane], bt = bn_t1[10 + lane], mu = bn_t1[20 + lane], vr = bn_t1[30 + lane];
    out[g * 10 + lane] = (o - mu) * gm * rsqrtf(vr + EPSf) + bt;
  }
  // out2 : (x,nx) @ fc2 (131x2) -> relu
  if (lane >= 10 && lane < 12) {
    int j = lane - 10;
    float o = fc2b[j];
    for (int k = 0; k < 128; ++k) o += xs[k] * fc2w[k * 2 + j];
    o += nx0 * fc2w[128 * 2 + j] + nx1 * fc2w[129 * 2 + j] + nx2 * fc2w[130 * 2 + j];
    o = fmaxf(o, 0.f);
    o2[j] = o;
    out[2560 + g * 2 + j] = o;
  }
  // x3 = BN_comb(concat(x, wf1, wf2, nx0, nx1, nx2))  (133)
  for (int k = lane; k < 133; k += 64) {
    float vsrc = (k < 128) ? xs[k]
               : (k == 128) ? wf1
               : (k == 129) ? wf2
               : (k == 130) ? nx0
               : (k == 131) ? nx1 : nx2;
    float gm = bn_comb[k], bt = bn_comb[133 + k], mu = bn_comb[266 + k], vr = bn_comb[399 + k];
    x3[k] = (vsrc - mu) * gm * rsqrtf(vr + EPSf) + bt;
  }
  __syncthreads();
  bool pred1 = o2[1] > o2[0];   // argmax with first-index tie-break
  if (lane < 4) {
    float o = fc3ab[lane];
    for (int k = 0; k < 133; ++k) o += x3[k] * fc3aw[k * 4 + lane];
    out[3072 + g * 9 + lane] = pred1 ? 0.f : o;
  }
  if (lane >= 4 && lane < 9) {
    int j = lane - 4;
    float o = fc3bb[j];
    for (int k = 0; k < 133; ++k) o += x3[k] * fc3bw[k * 5 + j];
    out[3072 + g * 9 + 4 + j] = pred1 ? o : 0.f;
  }
}

// ---------------- launch ----------------

extern "C" void kernel_launch(void* const* d_in, const int* in_sizes, int n_in,
                              void* d_out, int out_size, void* d_ws, size_t ws_size,
                              hipStream_t stream) {
  const float* x      = (const float*)d_in[0];
  const int*   ei     = (const int*)d_in[1];
  const int*   batch  = (const int*)d_in[2];
  const float* gf     = (const float*)d_in[3];
  // d_in[4] = task (unused)
  const float* gatW   = (const float*)d_in[5];
  const float* asrc   = (const float*)d_in[6];
  const float* adst   = (const float*)d_in[7];
  const float* gbias  = (const float*)d_in[8];
  const float* bn_emb = (const float*)d_in[9];
  const float* bn_t1  = (const float*)d_in[10];
  const float* bn_cb  = (const float*)d_in[11];
  const float* fc1w = (const float*)d_in[12]; const float* fc1b = (const float*)d_in[13];
  const float* fc2w = (const float*)d_in[14]; const float* fc2b = (const float*)d_in[15];
  const float* fc3aw = (const float*)d_in[16]; const float* fc3ab = (const float*)d_in[17];
  const float* fc3bw = (const float*)d_in[18]; const float* fc3bb = (const float*)d_in[19];
  float* out = (float*)d_out;

  char* p = (char*)d_ws;
  auto alloc = [&](size_t bytes) -> void* {
    void* r = (void*)p;
    p += (bytes + 255) & ~(size_t)255;
    return r;
  };
  float* hbuf = (float*)alloc((size_t)Nn * 128 * 4);
  float* xbuf = (float*)alloc((size_t)Nn * 128 * 4);
  int*   csr  = (int*)alloc((size_t)Mm * 4);
  int*   rp   = (int*)alloc((size_t)(Nn + 1) * 4);
  int*   fill = (int*)alloc((size_t)Nn * 4);
  float* es   = (float*)alloc((size_t)Nn * 4);
  float* ed   = (float*)alloc((size_t)Nn * 4);
  int*   blk  = (int*)alloc(512);
  float* xg   = (float*)alloc((size_t)Gg * 128 * 4);
  if ((size_t)(p - (char*)d_ws) > ws_size) return;  // ws too small: fail visibly

  const int* srcp = ei;
  const int* dstp = ei + Ee;

  // CSR by dst (edges + self-loops)
  k_init<<<(Nn + 255) / 256, 256, 0, stream>>>(fill, Nn);
  k_hist<<<(Ee + 255) / 256, 256, 0, stream>>>(dstp, fill, Ee);
  int nblk = (Nn + 1023) / 1024;
  k_scan1<<<nblk, 256, 0, stream>>>(fill, rp, blk, Nn);
  k_scan2<<<1, 128, 0, stream>>>(blk, nblk, rp + Nn);
  k_scan3<<<nblk, 256, 0, stream>>>(rp, fill, blk, Nn);
  k_scatter<<<(Mm + 255) / 256, 256, 0, stream>>>(srcp, dstp, fill, csr, Ee, Nn);

  // 3 GAT layers
  const float* xin = x;
  for (int l = 0; l < 3; ++l) {
    k_gemm<<<512, 256, 0, stream>>>(xin, gatW + (size_t)l * 128 * 128, hbuf, Nn);
    k_dots<<<(Nn + 3) / 4, 256, 0, stream>>>(hbuf, asrc + l * 128, adst + l * 128, es, ed, Nn);
    k_agg<<<(Nn + 3) / 4, 256, 0, stream>>>(hbuf, rp, csr, es, ed, gbias + l * 128, xbuf, Nn);
    xin = xbuf;
  }

  // pooling + BN_emb
  k_pool<<<Gg, 128, 0, stream>>>(xbuf, batch, bn_emb, xg, Nn);

  // heads
  k_heads<<<Gg, 64, 0, stream>>>(xg, gf, bn_t1, bn_cb,
                                 fc1w, fc1b, fc2w, fc2b, fc3aw, fc3ab, fc3bw, fc3bb, out);
}

// Round 2
// 1076.211 us; speedup vs baseline: 1.3095x; 1.3095x over previous
//
#include <hip/hip_runtime.h>
#include <hip/hip_fp16.h>
#include <math.h>

#define Nn 100000
#define Ee 1600000
#define Mm (Ee + Nn)
#define Gg 256
#define EPSf 1e-5f

// ---------------- CSR build ----------------

__global__ void k_init(int* __restrict__ deg, int n) {
  int i = blockIdx.x * 256 + threadIdx.x;
  if (i < n) deg[i] = 1;  // self-loop counts as 1
}

__global__ void k_hist(const int* __restrict__ dst, int* __restrict__ deg, int e) {
  int i = blockIdx.x * 256 + threadIdx.x;
  if (i < e) atomicAdd(&deg[dst[i]], 1);
}

__global__ void k_scan1(const int* __restrict__ deg, int* __restrict__ rp,
                        int* __restrict__ blk, int n) {
  __shared__ int s[256];
  int b = blockIdx.x, t = threadIdx.x;
  int i0 = b * 1024 + t * 4;
  int v0 = (i0     < n) ? deg[i0]     : 0;
  int v1 = (i0 + 1 < n) ? deg[i0 + 1] : 0;
  int v2 = (i0 + 2 < n) ? deg[i0 + 2] : 0;
  int v3 = (i0 + 3 < n) ? deg[i0 + 3] : 0;
  int sum = v0 + v1 + v2 + v3;
  s[t] = sum; __syncthreads();
  for (int o = 1; o < 256; o <<= 1) {
    int u = (t >= o) ? s[t - o] : 0;
    __syncthreads();
    s[t] += u;
    __syncthreads();
  }
  int excl = s[t] - sum;
  if (i0     < n) rp[i0]     = excl;
  if (i0 + 1 < n) rp[i0 + 1] = excl + v0;
  if (i0 + 2 < n) rp[i0 + 2] = excl + v0 + v1;
  if (i0 + 3 < n) rp[i0 + 3] = excl + v0 + v1 + v2;
  if (t == 255) blk[b] = s[255];
}

__global__ void k_scan2(int* __restrict__ blk, int nblk, int* __restrict__ tot) {
  __shared__ int s[128];
  int t = threadIdx.x;
  int v = (t < nblk) ? blk[t] : 0;
  s[t] = v; __syncthreads();
  for (int o = 1; o < 128; o <<= 1) {
    int u = (t >= o) ? s[t - o] : 0;
    __syncthreads(); s[t] += u; __syncthreads();
  }
  if (t < nblk) blk[t] = s[t] - v;          // exclusive block prefix
  if (t == nblk - 1) tot[0] = s[t];         // row_ptr[N] = E+N
}

__global__ void k_scan3(int* __restrict__ rp, int* __restrict__ fill,
                        const int* __restrict__ blk, int n) {
  int b = blockIdx.x;
  int add = blk[b];
  int i0 = b * 1024 + threadIdx.x * 4;
  #pragma unroll
  for (int k = 0; k < 4; ++k) {
    int i = i0 + k;
    if (i < n) { int v = rp[i] + add; rp[i] = v; fill[i] = v; }
  }
}

__global__ void k_scatter(const int* __restrict__ src, const int* __restrict__ dst,
                          int* __restrict__ fill, int* __restrict__ csr, int e, int n) {
  int i = blockIdx.x * 256 + threadIdx.x;
  if (i >= e + n) return;
  int s, v;
  if (i < e) { s = src[i]; v = dst[i]; } else { s = v = i - e; }
  int p = atomicAdd(&fill[v], 1);
  csr[p] = s;
}

// ---------------- GEMM: H = X(N,128) @ W(128,128), fp16 output ----------------
// W resident in 64 KB LDS; thread = 4 rows x 2 cols; float4 X loads.

__global__ __launch_bounds__(256) void k_gemm(const float* __restrict__ X,
                                              const float* __restrict__ Wg,
                                              __half2* __restrict__ H2, int n) {
  __shared__ float Wl[128 * 128];
  for (int i = threadIdx.x; i < 128 * 128; i += 256) Wl[i] = Wg[i];
  __syncthreads();
  int t = threadIdx.x;
  int cp = t & 63;            // col-pair index (cols 2cp, 2cp+1)
  int c0 = cp * 2;
  int rq = (t >> 6) * 4;      // 4 rows per thread, per wave
  int ngrp = n >> 4;          // n multiple of 16
  for (int grp = blockIdx.x; grp < ngrp; grp += gridDim.x) {
    int r0 = grp * 16 + rq;
    const float* xp = X + (size_t)r0 * 128;
    float a00 = 0, a01 = 0, a10 = 0, a11 = 0, a20 = 0, a21 = 0, a30 = 0, a31 = 0;
    for (int k = 0; k < 128; k += 4) {
      float4 xa = *reinterpret_cast<const float4*>(xp + k);
      float4 xb = *reinterpret_cast<const float4*>(xp + 128 + k);
      float4 xc = *reinterpret_cast<const float4*>(xp + 256 + k);
      float4 xd = *reinterpret_cast<const float4*>(xp + 384 + k);
      const float* fa = reinterpret_cast<const float*>(&xa);
      const float* fb = reinterpret_cast<const float*>(&xb);
      const float* fc = reinterpret_cast<const float*>(&xc);
      const float* fd = reinterpret_cast<const float*>(&xd);
      #pragma unroll
      for (int kk = 0; kk < 4; ++kk) {
        float2 w = *reinterpret_cast<const float2*>(&Wl[(k + kk) * 128 + c0]);
        a00 += fa[kk] * w.x; a01 += fa[kk] * w.y;
        a10 += fb[kk] * w.x; a11 += fb[kk] * w.y;
        a20 += fc[kk] * w.x; a21 += fc[kk] * w.y;
        a30 += fd[kk] * w.x; a31 += fd[kk] * w.y;
      }
    }
    H2[(size_t)(r0 + 0) * 64 + cp] = __float22half2_rn(make_float2(a00, a01));
    H2[(size_t)(r0 + 1) * 64 + cp] = __float22half2_rn(make_float2(a10, a11));
    H2[(size_t)(r0 + 2) * 64 + cp] = __float22half2_rn(make_float2(a20, a21));
    H2[(size_t)(r0 + 3) * 64 + cp] = __float22half2_rn(make_float2(a30, a31));
  }
}

// ---------------- per-node attention dots from fp16 H ----------------

__global__ __launch_bounds__(256) void k_dots(const __half2* __restrict__ H2,
                                              const float* __restrict__ asrc,
                                              const float* __restrict__ adst,
                                              float* __restrict__ es, float* __restrict__ ed, int n) {
  int v = blockIdx.x * 4 + (threadIdx.x >> 6);
  if (v >= n) return;
  int lane = threadIdx.x & 63;
  float2 h = __half22float2(H2[(size_t)v * 64 + lane]);
  float2 as = *reinterpret_cast<const float2*>(&asrc[2 * lane]);
  float2 ad = *reinterpret_cast<const float2*>(&adst[2 * lane]);
  float s = h.x * as.x + h.y * as.y;
  float d = h.x * ad.x + h.y * ad.y;
  #pragma unroll
  for (int o = 32; o; o >>= 1) { s += __shfl_xor(s, o); d += __shfl_xor(d, o); }
  if (lane == 0) { es[v] = s; ed[v] = d; }
}

// ---------------- aggregation: one wave per dst, edge state in registers ----------------

__global__ __launch_bounds__(256) void k_agg(const __half2* __restrict__ H2,
                                             const int* __restrict__ rp,
                                             const int* __restrict__ csr,
                                             const float* __restrict__ es,
                                             const float* __restrict__ ed,
                                             const float* __restrict__ bias,
                                             float* __restrict__ Xo, int n) {
  int v = blockIdx.x * 4 + (threadIdx.x >> 6);
  if (v >= n) return;
  int lane = threadIdx.x & 63;
  int r0 = rp[v], r1 = rp[v + 1];
  int deg = r1 - r0;
  float edv = ed[v];
  float2 acc = make_float2(0.f, 0.f);
  float inv;
  if (deg <= 64) {
    // fast path: lane j owns edge r0+j
    int u = 0;
    float e = -3.0e38f;
    if (lane < deg) {
      u = csr[r0 + lane];
      e = es[u] + edv;
      e = e > 0.f ? e : 0.2f * e;
    }
    float m = e;
    #pragma unroll
    for (int o = 32; o; o >>= 1) m = fmaxf(m, __shfl_xor(m, o));
    float pw = (lane < deg) ? __expf(e - m) : 0.f;
    float den = pw;
    #pragma unroll
    for (int o = 32; o; o >>= 1) den += __shfl_xor(den, o);
    inv = 1.f / den;
    for (int jj = 0; jj < deg; ++jj) {
      int uu = __shfl(u, jj);
      float w = __shfl(pw, jj);
      float2 hv = __half22float2(H2[(size_t)uu * 64 + lane]);
      acc.x += w * hv.x;
      acc.y += w * hv.y;
    }
  } else {
    // slow path (deg > 64): 3-pass
    float m = -3.0e38f;
    for (int j = r0 + lane; j < r1; j += 64) {
      float e = es[csr[j]] + edv;
      e = e > 0.f ? e : 0.2f * e;
      m = fmaxf(m, e);
    }
    #pragma unroll
    for (int o = 32; o; o >>= 1) m = fmaxf(m, __shfl_xor(m, o));
    float den = 0.f;
    for (int j = r0 + lane; j < r1; j += 64) {
      float e = es[csr[j]] + edv;
      e = e > 0.f ? e : 0.2f * e;
      den += __expf(e - m);
    }
    #pragma unroll
    for (int o = 32; o; o >>= 1) den += __shfl_xor(den, o);
    inv = 1.f / den;
    for (int j = r0; j < r1; ++j) {
      int u = csr[j];
      float e = es[u] + edv;
      e = e > 0.f ? e : 0.2f * e;
      float pw = __expf(e - m);
      float2 hv = __half22float2(H2[(size_t)u * 64 + lane]);
      acc.x += pw * hv.x;
      acc.y += pw * hv.y;
    }
  }
  float2 b = *reinterpret_cast<const float2*>(&bias[2 * lane]);
  float2 o;
  o.x = fmaxf(acc.x * inv + b.x, 0.f);
  o.y = fmaxf(acc.y * inv + b.y, 0.f);
  *reinterpret_cast<float2*>(&Xo[(size_t)v * 128 + 2 * lane]) = o;
}

// ---------------- pooling (mean per graph) + BN, 512 threads ----------------

__global__ __launch_bounds__(512) void k_pool(const float* __restrict__ X,
                                              const int* __restrict__ batch,
                                              const float* __restrict__ bn,
                                              float* __restrict__ xg, int n) {
  __shared__ float part[4][128];
  int g = blockIdx.x;
  int col = threadIdx.x & 127;
  int way = threadIdx.x >> 7;
  int lo = 0, hi = n;
  while (lo < hi) { int mid = (lo + hi) >> 1; if (batch[mid] < g) lo = mid + 1; else hi = mid; }
  int s0 = lo;
  lo = s0; hi = n;
  while (lo < hi) { int mid = (lo + hi) >> 1; if (batch[mid] < g + 1) lo = mid + 1; else hi = mid; }
  int e0 = lo;
  float acc = 0.f;
  for (int i = s0 + way; i < e0; i += 4) acc += X[(size_t)i * 128 + col];
  part[way][col] = acc;
  __syncthreads();
  if (way == 0) {
    float s = part[0][col] + part[1][col] + part[2][col] + part[3][col];
    float mean = (e0 > s0) ? s / (float)(e0 - s0) : 0.f;
    float gm = bn[col], bt = bn[128 + col], mu = bn[256 + col], vr = bn[384 + col];
    xg[g * 128 + col] = (mean - mu) * gm * rsqrtf(vr + EPSf) + bt;
  }
}

// ---------------- heads ----------------

__global__ void k_heads(const float* __restrict__ xg, const float* __restrict__ gf,
                        const float* __restrict__ bn_t1, const float* __restrict__ bn_comb,
                        const float* __restrict__ fc1w, const float* __restrict__ fc1b,
                        const float* __restrict__ fc2w, const float* __restrict__ fc2b,
                        const float* __restrict__ fc3aw, const float* __restrict__ fc3ab,
                        const float* __restrict__ fc3bw, const float* __restrict__ fc3bb,
                        float* __restrict__ out) {
  int g = blockIdx.x;
  int lane = threadIdx.x;   // block of 64 = one wave
  __shared__ float xs[128];
  __shared__ float x3[133];
  __shared__ float o2[2];
  xs[lane] = xg[g * 128 + lane];
  xs[lane + 64] = xg[g * 128 + 64 + lane];
  __syncthreads();
  const float* gfg = &gf[g * 8];
  float lev = gfg[7];
  float nx0 = gfg[5], nx1 = gfg[6], nx2 = gfg[7];
  float wf1 = gfg[2], wf2 = gfg[1];
  if (lane < 10) {
    float o = fc1b[lane];
    for (int k = 0; k < 128; ++k) o += xs[k] * fc1w[k * 10 + lane];
    o += lev * fc1w[128 * 10 + lane];
    o = fmaxf(o, 0.f);
    float gm = bn_t1[lane], bt = bn_t1[10 + lane], mu = bn_t1[20 + lane], vr = bn_t1[30 + lane];
    out[g * 10 + lane] = (o - mu) * gm * rsqrtf(vr + EPSf) + bt;
  }
  if (lane >= 10 && lane < 12) {
    int j = lane - 10;
    float o = fc2b[j];
    for (int k = 0; k < 128; ++k) o += xs[k] * fc2w[k * 2 + j];
    o += nx0 * fc2w[128 * 2 + j] + nx1 * fc2w[129 * 2 + j] + nx2 * fc2w[130 * 2 + j];
    o = fmaxf(o, 0.f);
    o2[j] = o;
    out[2560 + g * 2 + j] = o;
  }
  for (int k = lane; k < 133; k += 64) {
    float vsrc = (k < 128) ? xs[k]
               : (k == 128) ? wf1
               : (k == 129) ? wf2
               : (k == 130) ? nx0
               : (k == 131) ? nx1 : nx2;
    float gm = bn_comb[k], bt = bn_comb[133 + k], mu = bn_comb[266 + k], vr = bn_comb[399 + k];
    x3[k] = (vsrc - mu) * gm * rsqrtf(vr + EPSf) + bt;
  }
  __syncthreads();
  bool pred1 = o2[1] > o2[0];
  if (lane < 4) {
    float o = fc3ab[lane];
    for (int k = 0; k < 133; ++k) o += x3[k] * fc3aw[k * 4 + lane];
    out[3072 + g * 9 + lane] = pred1 ? 0.f : o;
  }
  if (lane >= 4 && lane < 9) {
    int j = lane - 4;
    float o = fc3bb[j];
    for (int k = 0; k < 133; ++k) o += x3[k] * fc3bw[k * 5 + j];
    out[3072 + g * 9 + 4 + j] = pred1 ? o : 0.f;
  }
}

// ---------------- launch ----------------

extern "C" void kernel_launch(void* const* d_in, const int* in_sizes, int n_in,
                              void* d_out, int out_size, void* d_ws, size_t ws_size,
                              hipStream_t stream) {
  const float* x      = (const float*)d_in[0];
  const int*   ei     = (const int*)d_in[1];
  const int*   batch  = (const int*)d_in[2];
  const float* gf     = (const float*)d_in[3];
  const float* gatW   = (const float*)d_in[5];
  const float* asrc   = (const float*)d_in[6];
  const float* adst   = (const float*)d_in[7];
  const float* gbias  = (const float*)d_in[8];
  const float* bn_emb = (const float*)d_in[9];
  const float* bn_t1  = (const float*)d_in[10];
  const float* bn_cb  = (const float*)d_in[11];
  const float* fc1w = (const float*)d_in[12]; const float* fc1b = (const float*)d_in[13];
  const float* fc2w = (const float*)d_in[14]; const float* fc2b = (const float*)d_in[15];
  const float* fc3aw = (const float*)d_in[16]; const float* fc3ab = (const float*)d_in[17];
  const float* fc3bw = (const float*)d_in[18]; const float* fc3bb = (const float*)d_in[19];
  float* out = (float*)d_out;

  char* p = (char*)d_ws;
  auto alloc = [&](size_t bytes) -> void* {
    void* r = (void*)p;
    p += (bytes + 255) & ~(size_t)255;
    return r;
  };
  __half2* hbuf = (__half2*)alloc((size_t)Nn * 64 * 4);   // fp16 H (25.6 MB)
  float* xbuf = (float*)alloc((size_t)Nn * 128 * 4);
  int*   csr  = (int*)alloc((size_t)Mm * 4);
  int*   rp   = (int*)alloc((size_t)(Nn + 1) * 4);
  int*   fill = (int*)alloc((size_t)Nn * 4);
  float* es   = (float*)alloc((size_t)Nn * 4);
  float* ed   = (float*)alloc((size_t)Nn * 4);
  int*   blk  = (int*)alloc(512);
  float* xg   = (float*)alloc((size_t)Gg * 128 * 4);
  if ((size_t)(p - (char*)d_ws) > ws_size) return;

  const int* srcp = ei;
  const int* dstp = ei + Ee;

  k_init<<<(Nn + 255) / 256, 256, 0, stream>>>(fill, Nn);
  k_hist<<<(Ee + 255) / 256, 256, 0, stream>>>(dstp, fill, Ee);
  int nblk = (Nn + 1023) / 1024;
  k_scan1<<<nblk, 256, 0, stream>>>(fill, rp, blk, Nn);
  k_scan2<<<1, 128, 0, stream>>>(blk, nblk, rp + Nn);
  k_scan3<<<nblk, 256, 0, stream>>>(rp, fill, blk, Nn);
  k_scatter<<<(Mm + 255) / 256, 256, 0, stream>>>(srcp, dstp, fill, csr, Ee, Nn);

  const float* xin = x;
  for (int l = 0; l < 3; ++l) {
    k_gemm<<<512, 256, 0, stream>>>(xin, gatW + (size_t)l * 128 * 128, hbuf, Nn);
    k_dots<<<(Nn + 3) / 4, 256, 0, stream>>>(hbuf, asrc + l * 128, adst + l * 128, es, ed, Nn);
    k_agg<<<(Nn + 3) / 4, 256, 0, stream>>>(hbuf, rp, csr, es, ed, gbias + l * 128, xbuf, Nn);
    xin = xbuf;
  }

  k_pool<<<Gg, 512, 0, stream>>>(xbuf, batch, bn_emb, xg, Nn);

  k_heads<<<Gg, 64, 0, stream>>>(xg, gf, bn_t1, bn_cb,
                                 fc1w, fc1b, fc2w, fc2b, fc3aw, fc3ab, fc3bw, fc3bb, out);
}

// Round 3
// 772.313 us; speedup vs baseline: 1.8248x; 1.3935x over previous
//
#include <hip/hip_runtime.h>
#include <math.h>

#define Nn 100000
#define Ee 1600000
#define Mm (Ee + Nn)
#define Gg 256
#define EPSf 1e-5f

typedef _Float16 f16x8 __attribute__((ext_vector_type(8)));
typedef _Float16 half4_t __attribute__((ext_vector_type(4)));
typedef float f32x4 __attribute__((ext_vector_type(4)));

// ---------------- CSR build ----------------

__global__ void k_init(int* __restrict__ deg, int n) {
  int i = blockIdx.x * 256 + threadIdx.x;
  if (i < n) deg[i] = 1;  // self-loop
}

__global__ void k_hist(const int* __restrict__ dst, int* __restrict__ deg, int e) {
  int i = blockIdx.x * 256 + threadIdx.x;
  if (i < e) atomicAdd(&deg[dst[i]], 1);
}

__global__ void k_scan1(const int* __restrict__ deg, int* __restrict__ rp,
                        int* __restrict__ blk, int n) {
  __shared__ int s[256];
  int b = blockIdx.x, t = threadIdx.x;
  int i0 = b * 1024 + t * 4;
  int v0 = (i0     < n) ? deg[i0]     : 0;
  int v1 = (i0 + 1 < n) ? deg[i0 + 1] : 0;
  int v2 = (i0 + 2 < n) ? deg[i0 + 2] : 0;
  int v3 = (i0 + 3 < n) ? deg[i0 + 3] : 0;
  int sum = v0 + v1 + v2 + v3;
  s[t] = sum; __syncthreads();
  for (int o = 1; o < 256; o <<= 1) {
    int u = (t >= o) ? s[t - o] : 0;
    __syncthreads();
    s[t] += u;
    __syncthreads();
  }
  int excl = s[t] - sum;
  if (i0     < n) rp[i0]     = excl;
  if (i0 + 1 < n) rp[i0 + 1] = excl + v0;
  if (i0 + 2 < n) rp[i0 + 2] = excl + v0 + v1;
  if (i0 + 3 < n) rp[i0 + 3] = excl + v0 + v1 + v2;
  if (t == 255) blk[b] = s[255];
}

__global__ void k_scan2(int* __restrict__ blk, int nblk, int* __restrict__ tot) {
  __shared__ int s[128];
  int t = threadIdx.x;
  int v = (t < nblk) ? blk[t] : 0;
  s[t] = v; __syncthreads();
  for (int o = 1; o < 128; o <<= 1) {
    int u = (t >= o) ? s[t - o] : 0;
    __syncthreads(); s[t] += u; __syncthreads();
  }
  if (t < nblk) blk[t] = s[t] - v;
  if (t == nblk - 1) tot[0] = s[t];
}

__global__ void k_scan3(int* __restrict__ rp, int* __restrict__ fill,
                        const int* __restrict__ blk, int n) {
  int b = blockIdx.x;
  int add = blk[b];
  int i0 = b * 1024 + threadIdx.x * 4;
  #pragma unroll
  for (int k = 0; k < 4; ++k) {
    int i = i0 + k;
    if (i < n) { int v = rp[i] + add; rp[i] = v; fill[i] = v; }
  }
}

__global__ void k_scatter(const int* __restrict__ src, const int* __restrict__ dst,
                          int* __restrict__ fill, int* __restrict__ csr, int e, int n) {
  int i = blockIdx.x * 256 + threadIdx.x;
  if (i >= e + n) return;
  int s, v;
  if (i < e) { s = src[i]; v = dst[i]; } else { s = v = i - e; }
  int p = atomicAdd(&fill[v], 1);
  csr[p] = s;
}

// ---------------- input conversions ----------------

__global__ void k_x2h(const float* __restrict__ X, half4_t* __restrict__ X16, int ntot4) {
  int i = blockIdx.x * 256 + threadIdx.x;
  if (i < ntot4) {
    float4 v = reinterpret_cast<const float4*>(X)[i];
    half4_t h = { (_Float16)v.x, (_Float16)v.y, (_Float16)v.z, (_Float16)v.w };
    X16[i] = h;
  }
}

// Wt[l][col][k] fp16 from W[l][k][col] f32
__global__ void k_prepW(const float* __restrict__ W, _Float16* __restrict__ Wt) {
  int l = blockIdx.x;
  const float* w = W + (size_t)l * 16384;
  _Float16* wt = Wt + (size_t)l * 16384;
  for (int i = threadIdx.x; i < 16384; i += 256) {
    int k = i >> 7, c = i & 127;
    wt[c * 128 + k] = (_Float16)w[i];
  }
}

// ---------------- MFMA GEMM: H = X16 @ W  (fp16 in, fp16 out, f32 accum) ----------------
// Computes H^T tiles: A = W^T frag, B = X^T frag. Fuses es/ed dot products.
// Block = 4 waves; each wave does 32 rows x 128 cols. No LDS.

__global__ __launch_bounds__(256) void k_gemm(const _Float16* __restrict__ X16,
                                              const _Float16* __restrict__ Wt,
                                              const float* __restrict__ asrc,
                                              const float* __restrict__ adst,
                                              _Float16* __restrict__ H,
                                              float* __restrict__ es,
                                              float* __restrict__ ed, int n) {
  int wid = threadIdx.x >> 6;
  int lane = threadIdx.x & 63;
  int r0 = blockIdx.x * 128 + wid * 32;
  if (r0 >= n) return;
  int lo16 = lane & 15, q = lane >> 4;

  f32x4 acc0[8] = {};
  f32x4 acc1[8] = {};
  const _Float16* xb0 = X16 + (size_t)(r0 + lo16) * 128 + q * 8;
  const _Float16* xb1 = xb0 + 16 * 128;
  const _Float16* wb  = Wt + (size_t)lo16 * 128 + q * 8;

  #pragma unroll
  for (int kk = 0; kk < 4; ++kk) {
    f16x8 b0 = *reinterpret_cast<const f16x8*>(xb0 + kk * 32);
    f16x8 b1 = *reinterpret_cast<const f16x8*>(xb1 + kk * 32);
    #pragma unroll
    for (int c = 0; c < 8; ++c) {
      f16x8 a = *reinterpret_cast<const f16x8*>(wb + (size_t)c * 2048 + kk * 32);
      acc0[c] = __builtin_amdgcn_mfma_f32_16x16x32_f16(a, b0, acc0[c], 0, 0, 0);
      acc1[c] = __builtin_amdgcn_mfma_f32_16x16x32_f16(a, b1, acc1[c], 0, 0, 0);
    }
  }

  // fused es/ed:  es[row] = sum_col H[row][col]*asrc[col]
  float es0 = 0.f, es1 = 0.f, ed0 = 0.f, ed1 = 0.f;
  #pragma unroll
  for (int c = 0; c < 8; ++c) {
    float4 as = reinterpret_cast<const float4*>(asrc)[c * 4 + q];
    float4 ad = reinterpret_cast<const float4*>(adst)[c * 4 + q];
    es0 += acc0[c][0] * as.x + acc0[c][1] * as.y + acc0[c][2] * as.z + acc0[c][3] * as.w;
    ed0 += acc0[c][0] * ad.x + acc0[c][1] * ad.y + acc0[c][2] * ad.z + acc0[c][3] * ad.w;
    es1 += acc1[c][0] * as.x + acc1[c][1] * as.y + acc1[c][2] * as.z + acc1[c][3] * as.w;
    ed1 += acc1[c][0] * ad.x + acc1[c][1] * ad.y + acc1[c][2] * ad.z + acc1[c][3] * ad.w;
  }
  es0 += __shfl_xor(es0, 16); es0 += __shfl_xor(es0, 32);
  ed0 += __shfl_xor(ed0, 16); ed0 += __shfl_xor(ed0, 32);
  es1 += __shfl_xor(es1, 16); es1 += __shfl_xor(es1, 32);
  ed1 += __shfl_xor(ed1, 16); ed1 += __shfl_xor(ed1, 32);

  // store H (half4 per lane: 4 consecutive cols of one row)
  half4_t* H4 = reinterpret_cast<half4_t*>(H);
  int row0 = r0 + lo16;
  #pragma unroll
  for (int c = 0; c < 8; ++c) {
    half4_t h0 = { (_Float16)acc0[c][0], (_Float16)acc0[c][1],
                   (_Float16)acc0[c][2], (_Float16)acc0[c][3] };
    half4_t h1 = { (_Float16)acc1[c][0], (_Float16)acc1[c][1],
                   (_Float16)acc1[c][2], (_Float16)acc1[c][3] };
    H4[(size_t)row0 * 32 + c * 4 + q]        = h0;
    H4[(size_t)(row0 + 16) * 32 + c * 4 + q] = h1;
  }
  if (lane < 16) {
    es[r0 + lane] = es0;       ed[r0 + lane] = ed0;
    es[r0 + 16 + lane] = es1;  ed[r0 + 16 + lane] = ed1;
  }
}

// ---------------- aggregation: one wave per dst ----------------

__global__ __launch_bounds__(256) void k_agg(const _Float16* __restrict__ H,
                                             const int* __restrict__ rp,
                                             const int* __restrict__ csr,
                                             const float* __restrict__ es,
                                             const float* __restrict__ ed,
                                             const float* __restrict__ bias,
                                             _Float16* __restrict__ Xo, int n) {
  int v = blockIdx.x * 4 + (threadIdx.x >> 6);
  if (v >= n) return;
  int lane = threadIdx.x & 63;
  int c32 = lane & 31;
  int r0 = rp[v], r1 = rp[v + 1];
  int deg = r1 - r0;
  float edv = ed[v];
  const half4_t* H4 = reinterpret_cast<const half4_t*>(H);
  float ax = 0.f, ay = 0.f, az = 0.f, aw = 0.f;
  float inv;

  if (deg <= 64) {
    int u = 0;
    float e = -3.0e38f;
    if (lane < deg) {
      u = csr[r0 + lane];
      e = es[u] + edv;
      e = e > 0.f ? e : 0.2f * e;
    }
    float m = e;
    #pragma unroll
    for (int o = 32; o; o >>= 1) m = fmaxf(m, __shfl_xor(m, o));
    float pw = (lane < deg) ? __expf(e - m) : 0.f;
    float den = pw;
    #pragma unroll
    for (int o = 32; o; o >>= 1) den += __shfl_xor(den, o);
    inv = 1.f / den;
    int npair = deg >> 1;
    for (int i = 0; i < npair; ++i) {
      int idx = 2 * i + (lane >> 5);
      int uu = __shfl(u, idx);
      float ww = __shfl(pw, idx);
      half4_t hv = H4[(size_t)uu * 32 + c32];
      ax += ww * (float)hv[0]; ay += ww * (float)hv[1];
      az += ww * (float)hv[2]; aw += ww * (float)hv[3];
    }
    if (deg & 1) {
      int uu = __shfl(u, deg - 1);
      float ww = __shfl(pw, deg - 1);
      if (lane < 32) {
        half4_t hv = H4[(size_t)uu * 32 + c32];
        ax += ww * (float)hv[0]; ay += ww * (float)hv[1];
        az += ww * (float)hv[2]; aw += ww * (float)hv[3];
      }
    }
  } else {
    float m = -3.0e38f;
    for (int j = r0 + lane; j < r1; j += 64) {
      float e = es[csr[j]] + edv;
      e = e > 0.f ? e : 0.2f * e;
      m = fmaxf(m, e);
    }
    #pragma unroll
    for (int o = 32; o; o >>= 1) m = fmaxf(m, __shfl_xor(m, o));
    float den = 0.f;
    for (int j = r0 + lane; j < r1; j += 64) {
      float e = es[csr[j]] + edv;
      e = e > 0.f ? e : 0.2f * e;
      den += __expf(e - m);
    }
    #pragma unroll
    for (int o = 32; o; o >>= 1) den += __shfl_xor(den, o);
    inv = 1.f / den;
    for (int j = r0; j < r1 - 1; j += 2) {
      int uu = csr[j + (lane >> 5)];
      float e = es[uu] + edv;
      e = e > 0.f ? e : 0.2f * e;
      float ww = __expf(e - m);
      half4_t hv = H4[(size_t)uu * 32 + c32];
      ax += ww * (float)hv[0]; ay += ww * (float)hv[1];
      az += ww * (float)hv[2]; aw += ww * (float)hv[3];
    }
    if (deg & 1) {
      int uu = csr[r1 - 1];
      float e = es[uu] + edv;
      e = e > 0.f ? e : 0.2f * e;
      float ww = __expf(e - m);
      if (lane < 32) {
        half4_t hv = H4[(size_t)uu * 32 + c32];
        ax += ww * (float)hv[0]; ay += ww * (float)hv[1];
        az += ww * (float)hv[2]; aw += ww * (float)hv[3];
      }
    }
  }
  ax += __shfl_xor(ax, 32);
  ay += __shfl_xor(ay, 32);
  az += __shfl_xor(az, 32);
  aw += __shfl_xor(aw, 32);
  if (lane < 32) {
    float4 b = reinterpret_cast<const float4*>(bias)[c32];
    half4_t o = { (_Float16)fmaxf(ax * inv + b.x, 0.f),
                  (_Float16)fmaxf(ay * inv + b.y, 0.f),
                  (_Float16)fmaxf(az * inv + b.z, 0.f),
                  (_Float16)fmaxf(aw * inv + b.w, 0.f) };
    reinterpret_cast<half4_t*>(Xo)[(size_t)v * 32 + c32] = o;
  }
}

// ---------------- pooling (mean per graph) + BN ----------------

__global__ __launch_bounds__(512) void k_pool(const _Float16* __restrict__ X16,
                                              const int* __restrict__ batch,
                                              const float* __restrict__ bn,
                                              float* __restrict__ xg, int n) {
  __shared__ float part[4][128];
  int g = blockIdx.x;
  int col = threadIdx.x & 127;
  int way = threadIdx.x >> 7;
  int lo = 0, hi = n;
  while (lo < hi) { int mid = (lo + hi) >> 1; if (batch[mid] < g) lo = mid + 1; else hi = mid; }
  int s0 = lo;
  lo = s0; hi = n;
  while (lo < hi) { int mid = (lo + hi) >> 1; if (batch[mid] < g + 1) lo = mid + 1; else hi = mid; }
  int e0 = lo;
  float acc = 0.f;
  for (int i = s0 + way; i < e0; i += 4) acc += (float)X16[(size_t)i * 128 + col];
  part[way][col] = acc;
  __syncthreads();
  if (way == 0) {
    float s = part[0][col] + part[1][col] + part[2][col] + part[3][col];
    float mean = (e0 > s0) ? s / (float)(e0 - s0) : 0.f;
    float gm = bn[col], bt = bn[128 + col], mu = bn[256 + col], vr = bn[384 + col];
    xg[g * 128 + col] = (mean - mu) * gm * rsqrtf(vr + EPSf) + bt;
  }
}

// ---------------- heads ----------------

__global__ void k_heads(const float* __restrict__ xg, const float* __restrict__ gf,
                        const float* __restrict__ bn_t1, const float* __restrict__ bn_comb,
                        const float* __restrict__ fc1w, const float* __restrict__ fc1b,
                        const float* __restrict__ fc2w, const float* __restrict__ fc2b,
                        const float* __restrict__ fc3aw, const float* __restrict__ fc3ab,
                        const float* __restrict__ fc3bw, const float* __restrict__ fc3bb,
                        float* __restrict__ out) {
  int g = blockIdx.x;
  int lane = threadIdx.x;
  __shared__ float xs[128];
  __shared__ float x3[133];
  __shared__ float o2[2];
  xs[lane] = xg[g * 128 + lane];
  xs[lane + 64] = xg[g * 128 + 64 + lane];
  __syncthreads();
  const float* gfg = &gf[g * 8];
  float lev = gfg[7];
  float nx0 = gfg[5], nx1 = gfg[6], nx2 = gfg[7];
  float wf1 = gfg[2], wf2 = gfg[1];
  if (lane < 10) {
    float o = fc1b[lane];
    for (int k = 0; k < 128; ++k) o += xs[k] * fc1w[k * 10 + lane];
    o += lev * fc1w[128 * 10 + lane];
    o = fmaxf(o, 0.f);
    float gm = bn_t1[lane], bt = bn_t1[10 + lane], mu = bn_t1[20 + lane], vr = bn_t1[30 + lane];
    out[g * 10 + lane] = (o - mu) * gm * rsqrtf(vr + EPSf) + bt;
  }
  if (lane >= 10 && lane < 12) {
    int j = lane - 10;
    float o = fc2b[j];
    for (int k = 0; k < 128; ++k) o += xs[k] * fc2w[k * 2 + j];
    o += nx0 * fc2w[128 * 2 + j] + nx1 * fc2w[129 * 2 + j] + nx2 * fc2w[130 * 2 + j];
    o = fmaxf(o, 0.f);
    o2[j] = o;
    out[2560 + g * 2 + j] = o;
  }
  for (int k = lane; k < 133; k += 64) {
    float vsrc = (k < 128) ? xs[k]
               : (k == 128) ? wf1
               : (k == 129) ? wf2
               : (k == 130) ? nx0
               : (k == 131) ? nx1 : nx2;
    float gm = bn_comb[k], bt = bn_comb[133 + k], mu = bn_comb[266 + k], vr = bn_comb[399 + k];
    x3[k] = (vsrc - mu) * gm * rsqrtf(vr + EPSf) + bt;
  }
  __syncthreads();
  bool pred1 = o2[1] > o2[0];
  if (lane < 4) {
    float o = fc3ab[lane];
    for (int k = 0; k < 133; ++k) o += x3[k] * fc3aw[k * 4 + lane];
    out[3072 + g * 9 + lane] = pred1 ? 0.f : o;
  }
  if (lane >= 4 && lane < 9) {
    int j = lane - 4;
    float o = fc3bb[j];
    for (int k = 0; k < 133; ++k) o += x3[k] * fc3bw[k * 5 + j];
    out[3072 + g * 9 + 4 + j] = pred1 ? o : 0.f;
  }
}

// ---------------- launch ----------------

extern "C" void kernel_launch(void* const* d_in, const int* in_sizes, int n_in,
                              void* d_out, int out_size, void* d_ws, size_t ws_size,
                              hipStream_t stream) {
  const float* x      = (const float*)d_in[0];
  const int*   ei     = (const int*)d_in[1];
  const int*   batch  = (const int*)d_in[2];
  const float* gf     = (const float*)d_in[3];
  const float* gatW   = (const float*)d_in[5];
  const float* asrc   = (const float*)d_in[6];
  const float* adst   = (const float*)d_in[7];
  const float* gbias  = (const float*)d_in[8];
  const float* bn_emb = (const float*)d_in[9];
  const float* bn_t1  = (const float*)d_in[10];
  const float* bn_cb  = (const float*)d_in[11];
  const float* fc1w = (const float*)d_in[12]; const float* fc1b = (const float*)d_in[13];
  const float* fc2w = (const float*)d_in[14]; const float* fc2b = (const float*)d_in[15];
  const float* fc3aw = (const float*)d_in[16]; const float* fc3ab = (const float*)d_in[17];
  const float* fc3bw = (const float*)d_in[18]; const float* fc3bb = (const float*)d_in[19];
  float* out = (float*)d_out;

  char* p = (char*)d_ws;
  auto alloc = [&](size_t bytes) -> void* {
    void* r = (void*)p;
    p += (bytes + 255) & ~(size_t)255;
    return r;
  };
  _Float16* x16a = (_Float16*)alloc((size_t)Nn * 128 * 2);
  _Float16* x16b = (_Float16*)alloc((size_t)Nn * 128 * 2);
  _Float16* hbuf = (_Float16*)alloc((size_t)Nn * 128 * 2);
  _Float16* wt   = (_Float16*)alloc((size_t)3 * 16384 * 2);
  int*   csr  = (int*)alloc((size_t)Mm * 4);
  int*   rp   = (int*)alloc((size_t)(Nn + 1) * 4);
  int*   fill = (int*)alloc((size_t)Nn * 4);
  float* es   = (float*)alloc((size_t)Nn * 4);
  float* ed   = (float*)alloc((size_t)Nn * 4);
  int*   blk  = (int*)alloc(512);
  float* xg   = (float*)alloc((size_t)Gg * 128 * 4);
  if ((size_t)(p - (char*)d_ws) > ws_size) return;

  const int* srcp = ei;
  const int* dstp = ei + Ee;

  // conversions
  k_x2h<<<(Nn * 32 + 255) / 256, 256, 0, stream>>>(x, (half4_t*)x16a, Nn * 32);
  k_prepW<<<3, 256, 0, stream>>>(gatW, wt);

  // CSR by dst
  k_init<<<(Nn + 255) / 256, 256, 0, stream>>>(fill, Nn);
  k_hist<<<(Ee + 255) / 256, 256, 0, stream>>>(dstp, fill, Ee);
  int nblk = (Nn + 1023) / 1024;
  k_scan1<<<nblk, 256, 0, stream>>>(fill, rp, blk, Nn);
  k_scan2<<<1, 128, 0, stream>>>(blk, nblk, rp + Nn);
  k_scan3<<<nblk, 256, 0, stream>>>(rp, fill, blk, Nn);
  k_scatter<<<(Mm + 255) / 256, 256, 0, stream>>>(srcp, dstp, fill, csr, Ee, Nn);

  // 3 GAT layers (ping-pong fp16 feature buffers)
  _Float16* xin = x16a;
  _Float16* xout = x16b;
  int ngrid = (Nn + 127) / 128;
  for (int l = 0; l < 3; ++l) {
    k_gemm<<<ngrid, 256, 0, stream>>>(xin, wt + (size_t)l * 16384,
                                      asrc + l * 128, adst + l * 128,
                                      hbuf, es, ed, Nn);
    k_agg<<<(Nn + 3) / 4, 256, 0, stream>>>(hbuf, rp, csr, es, ed,
                                            gbias + l * 128, xout, Nn);
    _Float16* t = xin; xin = xout; xout = t;
  }
  // after 3 swaps, final features are in xin

  k_pool<<<Gg, 512, 0, stream>>>(xin, batch, bn_emb, xg, Nn);

  k_heads<<<Gg, 64, 0, stream>>>(xg, gf, bn_t1, bn_cb,
                                 fc1w, fc1b, fc2w, fc2b, fc3aw, fc3ab, fc3bw, fc3bb, out);
}

// Round 4
// 554.357 us; speedup vs baseline: 2.5422x; 1.3932x over previous
//
#include <hip/hip_runtime.h>
#include <math.h>

#define Nn 100000
#define Ee 1600000
#define Mm (Ee + Nn)
#define Gg 256
#define EPSf 1e-5f
#define NB 391          // buckets of 256 nodes: (Nn+255)>>8
#define EPB 4096        // edges per binning block
#define NEB 391         // ceil(Ee/EPB)

typedef _Float16 f16x8 __attribute__((ext_vector_type(8)));
typedef _Float16 half4_t __attribute__((ext_vector_type(4)));
typedef float f32x4 __attribute__((ext_vector_type(4)));

// ---------------- bucketed CSR build ----------------

__global__ void k_zero(int* __restrict__ a, int n) {
  int i = blockIdx.x * 256 + threadIdx.x;
  if (i < n) a[i] = 0;
}

// histogram of dst buckets
__global__ __launch_bounds__(256) void k_bcount(const int* __restrict__ dst,
                                                int* __restrict__ bcnt, int e) {
  __shared__ int lcnt[NB];
  int t = threadIdx.x;
  for (int i = t; i < NB; i += 256) lcnt[i] = 0;
  __syncthreads();
  int base = blockIdx.x * EPB;
  #pragma unroll
  for (int i = 0; i < 16; ++i) {
    int idx = base + i * 256 + t;
    if (idx < e) atomicAdd(&lcnt[dst[idx] >> 8], 1);
  }
  __syncthreads();
  for (int i = t; i < NB; i += 256)
    if (lcnt[i]) atomicAdd(&bcnt[i], lcnt[i]);
}

// single-block scan: pair bases (edges only) and csr bases (edges + self-loops)
__global__ __launch_bounds__(512) void k_bscan(const int* __restrict__ bcnt,
                                               int* __restrict__ pairBase,
                                               int* __restrict__ tailA,
                                               int* __restrict__ bbase,
                                               int* __restrict__ rp) {
  __shared__ int s1[512], s2[512];
  int t = threadIdx.x;
  int c = (t < NB) ? bcnt[t] : 0;
  int nib = (t < NB) ? min(Nn - (t << 8), 256) : 0;
  s1[t] = c; s2[t] = c + nib;
  __syncthreads();
  for (int o = 1; o < 512; o <<= 1) {
    int u1 = (t >= o) ? s1[t - o] : 0;
    int u2 = (t >= o) ? s2[t - o] : 0;
    __syncthreads();
    s1[t] += u1; s2[t] += u2;
    __syncthreads();
  }
  if (t < NB) {
    pairBase[t] = s1[t] - c;
    tailA[t]    = s1[t] - c;
    bbase[t]    = s2[t] - (c + nib);
  }
  if (t == 0) rp[Nn] = Mm;
}

// bin edges into (dst,src) pairs grouped by bucket
__global__ __launch_bounds__(256) void k_bin(const int* __restrict__ src,
                                             const int* __restrict__ dst,
                                             int* __restrict__ tailA,
                                             int2* __restrict__ pairs, int e) {
  __shared__ int lcnt[NB];
  __shared__ int lbase[NB];
  int t = threadIdx.x;
  for (int i = t; i < NB; i += 256) lcnt[i] = 0;
  __syncthreads();
  int base = blockIdx.x * EPB;
  int d[16], s[16], br[16];
  #pragma unroll
  for (int i = 0; i < 16; ++i) {
    int idx = base + i * 256 + t;
    if (idx < e) {
      d[i] = dst[idx]; s[i] = src[idx];
      br[i] = atomicAdd(&lcnt[d[i] >> 8], 1);
    } else br[i] = -1;
  }
  __syncthreads();
  for (int i = t; i < NB; i += 256)
    if (lcnt[i] > 0) lbase[i] = atomicAdd(&tailA[i], lcnt[i]);
  __syncthreads();
  #pragma unroll
  for (int i = 0; i < 16; ++i) {
    if (br[i] >= 0) {
      int b = d[i] >> 8;
      pairs[lbase[b] + br[i]] = make_int2(d[i], s[i]);
    }
  }
}

// one block per bucket: build rp + place csr entries (L2-local writes)
__global__ __launch_bounds__(256) void k_place(const int2* __restrict__ pairs,
                                               const int* __restrict__ pairBase,
                                               const int* __restrict__ bcnt,
                                               const int* __restrict__ bbase,
                                               int* __restrict__ rp,
                                               int* __restrict__ csr) {
  __shared__ int cnt[256];
  __shared__ int ofs[256];
  int b = blockIdx.x, t = threadIdx.x;
  int v0 = b << 8;
  int nib = min(Nn - v0, 256);
  int pb = pairBase[b], pc = bcnt[b];
  int cb = bbase[b];
  cnt[t] = (t < nib) ? 1 : 0;   // self-loop contributes 1
  __syncthreads();
  for (int j = t; j < pc; j += 256) {
    int2 p = pairs[pb + j];
    atomicAdd(&cnt[p.x - v0], 1);
  }
  __syncthreads();
  int c = cnt[t];
  ofs[t] = c;
  __syncthreads();
  for (int o = 1; o < 256; o <<= 1) {
    int u = (t >= o) ? ofs[t - o] : 0;
    __syncthreads(); ofs[t] += u; __syncthreads();
  }
  int excl = ofs[t] - c;
  if (t < nib) rp[v0 + t] = cb + excl;
  cnt[t] = excl;               // reuse as fill counter
  __syncthreads();
  if (t < nib) {
    int pos = atomicAdd(&cnt[t], 1);
    csr[cb + pos] = v0 + t;    // self-loop
  }
  __syncthreads();
  for (int j = t; j < pc; j += 256) {
    int2 p = pairs[pb + j];
    int pos = atomicAdd(&cnt[p.x - v0], 1);
    csr[cb + pos] = p.y;
  }
}

// ---------------- input conversions ----------------

__global__ void k_x2h(const float* __restrict__ X, half4_t* __restrict__ X16, int ntot4) {
  int i = blockIdx.x * 256 + threadIdx.x;
  if (i < ntot4) {
    float4 v = reinterpret_cast<const float4*>(X)[i];
    half4_t h = { (_Float16)v.x, (_Float16)v.y, (_Float16)v.z, (_Float16)v.w };
    X16[i] = h;
  }
}

__global__ void k_prepW(const float* __restrict__ W, _Float16* __restrict__ Wt) {
  int l = blockIdx.x;
  const float* w = W + (size_t)l * 16384;
  _Float16* wt = Wt + (size_t)l * 16384;
  for (int i = threadIdx.x; i < 16384; i += 256) {
    int k = i >> 7, c = i & 127;
    wt[c * 128 + k] = (_Float16)w[i];
  }
}

// ---------------- MFMA GEMM: H = X16 @ W (fp16 in/out, f32 accum), fused es/ed ----------------

__global__ __launch_bounds__(256) void k_gemm(const _Float16* __restrict__ X16,
                                              const _Float16* __restrict__ Wt,
                                              const float* __restrict__ asrc,
                                              const float* __restrict__ adst,
                                              _Float16* __restrict__ H,
                                              float* __restrict__ es,
                                              float* __restrict__ ed, int n) {
  int wid = threadIdx.x >> 6;
  int lane = threadIdx.x & 63;
  int r0 = blockIdx.x * 128 + wid * 32;
  if (r0 >= n) return;
  int lo16 = lane & 15, q = lane >> 4;

  f32x4 acc0[8] = {};
  f32x4 acc1[8] = {};
  const _Float16* xb0 = X16 + (size_t)(r0 + lo16) * 128 + q * 8;
  const _Float16* xb1 = xb0 + 16 * 128;
  const _Float16* wb  = Wt + (size_t)lo16 * 128 + q * 8;

  #pragma unroll
  for (int kk = 0; kk < 4; ++kk) {
    f16x8 b0 = *reinterpret_cast<const f16x8*>(xb0 + kk * 32);
    f16x8 b1 = *reinterpret_cast<const f16x8*>(xb1 + kk * 32);
    #pragma unroll
    for (int c = 0; c < 8; ++c) {
      f16x8 a = *reinterpret_cast<const f16x8*>(wb + (size_t)c * 2048 + kk * 32);
      acc0[c] = __builtin_amdgcn_mfma_f32_16x16x32_f16(a, b0, acc0[c], 0, 0, 0);
      acc1[c] = __builtin_amdgcn_mfma_f32_16x16x32_f16(a, b1, acc1[c], 0, 0, 0);
    }
  }

  float es0 = 0.f, es1 = 0.f, ed0 = 0.f, ed1 = 0.f;
  #pragma unroll
  for (int c = 0; c < 8; ++c) {
    float4 as = reinterpret_cast<const float4*>(asrc)[c * 4 + q];
    float4 ad = reinterpret_cast<const float4*>(adst)[c * 4 + q];
    es0 += acc0[c][0] * as.x + acc0[c][1] * as.y + acc0[c][2] * as.z + acc0[c][3] * as.w;
    ed0 += acc0[c][0] * ad.x + acc0[c][1] * ad.y + acc0[c][2] * ad.z + acc0[c][3] * ad.w;
    es1 += acc1[c][0] * as.x + acc1[c][1] * as.y + acc1[c][2] * as.z + acc1[c][3] * as.w;
    ed1 += acc1[c][0] * ad.x + acc1[c][1] * ad.y + acc1[c][2] * ad.z + acc1[c][3] * ad.w;
  }
  es0 += __shfl_xor(es0, 16); es0 += __shfl_xor(es0, 32);
  ed0 += __shfl_xor(ed0, 16); ed0 += __shfl_xor(ed0, 32);
  es1 += __shfl_xor(es1, 16); es1 += __shfl_xor(es1, 32);
  ed1 += __shfl_xor(ed1, 16); ed1 += __shfl_xor(ed1, 32);

  half4_t* H4 = reinterpret_cast<half4_t*>(H);
  int row0 = r0 + lo16;
  #pragma unroll
  for (int c = 0; c < 8; ++c) {
    half4_t h0 = { (_Float16)acc0[c][0], (_Float16)acc0[c][1],
                   (_Float16)acc0[c][2], (_Float16)acc0[c][3] };
    half4_t h1 = { (_Float16)acc1[c][0], (_Float16)acc1[c][1],
                   (_Float16)acc1[c][2], (_Float16)acc1[c][3] };
    H4[(size_t)row0 * 32 + c * 4 + q]        = h0;
    H4[(size_t)(row0 + 16) * 32 + c * 4 + q] = h1;
  }
  if (lane < 16) {
    es[r0 + lane] = es0;       ed[r0 + lane] = ed0;
    es[r0 + 16 + lane] = es1;  ed[r0 + 16 + lane] = ed1;
  }
}

// ---------------- aggregation: one wave per dst, 4 edges/iter ----------------

__global__ __launch_bounds__(256) void k_agg(const _Float16* __restrict__ H,
                                             const int* __restrict__ rp,
                                             const int* __restrict__ csr,
                                             const float* __restrict__ es,
                                             const float* __restrict__ ed,
                                             const float* __restrict__ bias,
                                             _Float16* __restrict__ Xo, int n) {
  int v = blockIdx.x * 4 + (threadIdx.x >> 6);
  if (v >= n) return;
  int lane = threadIdx.x & 63;
  int g = lane >> 4;      // edge-group 0..3
  int s = lane & 15;      // 8-col chunk index
  int r0 = rp[v], r1 = rp[v + 1];
  int deg = r1 - r0;
  float edv = ed[v];
  const f16x8* H8 = reinterpret_cast<const f16x8*>(H);
  float acc[8] = {};
  float inv;

  if (deg <= 64) {
    int u = 0;
    float e = -3.0e38f;
    if (lane < deg) {
      u = csr[r0 + lane];
      e = es[u] + edv;
      e = e > 0.f ? e : 0.2f * e;
    }
    float m = e;
    #pragma unroll
    for (int o = 32; o; o >>= 1) m = fmaxf(m, __shfl_xor(m, o));
    float pw = (lane < deg) ? __expf(e - m) : 0.f;
    float den = pw;
    #pragma unroll
    for (int o = 32; o; o >>= 1) den += __shfl_xor(den, o);
    inv = 1.f / den;
    for (int i = 0; i < deg; i += 4) {
      int idx = i + g;
      if (idx < deg) {
        int uu = __shfl(u, idx);
        float ww = __shfl(pw, idx);
        f16x8 hv = H8[(size_t)uu * 16 + s];
        #pragma unroll
        for (int k2 = 0; k2 < 8; ++k2) acc[k2] += ww * (float)hv[k2];
      }
    }
  } else {
    float m = -3.0e38f;
    for (int j = r0 + lane; j < r1; j += 64) {
      float e = es[csr[j]] + edv;
      e = e > 0.f ? e : 0.2f * e;
      m = fmaxf(m, e);
    }
    #pragma unroll
    for (int o = 32; o; o >>= 1) m = fmaxf(m, __shfl_xor(m, o));
    float den = 0.f;
    for (int j = r0 + lane; j < r1; j += 64) {
      float e = es[csr[j]] + edv;
      e = e > 0.f ? e : 0.2f * e;
      den += __expf(e - m);
    }
    #pragma unroll
    for (int o = 32; o; o >>= 1) den += __shfl_xor(den, o);
    inv = 1.f / den;
    for (int j = r0; j < r1; j += 4) {
      int idx = j + g;
      if (idx < r1) {
        int uu = csr[idx];
        float e = es[uu] + edv;
        e = e > 0.f ? e : 0.2f * e;
        float ww = __expf(e - m);
        f16x8 hv = H8[(size_t)uu * 16 + s];
        #pragma unroll
        for (int k2 = 0; k2 < 8; ++k2) acc[k2] += ww * (float)hv[k2];
      }
    }
  }
  #pragma unroll
  for (int k2 = 0; k2 < 8; ++k2) {
    acc[k2] += __shfl_xor(acc[k2], 16);
    acc[k2] += __shfl_xor(acc[k2], 32);
  }
  if (lane < 16) {
    float4 b0 = reinterpret_cast<const float4*>(bias)[s * 2];
    float4 b1 = reinterpret_cast<const float4*>(bias)[s * 2 + 1];
    f16x8 o;
    o[0] = (_Float16)fmaxf(acc[0] * inv + b0.x, 0.f);
    o[1] = (_Float16)fmaxf(acc[1] * inv + b0.y, 0.f);
    o[2] = (_Float16)fmaxf(acc[2] * inv + b0.z, 0.f);
    o[3] = (_Float16)fmaxf(acc[3] * inv + b0.w, 0.f);
    o[4] = (_Float16)fmaxf(acc[4] * inv + b1.x, 0.f);
    o[5] = (_Float16)fmaxf(acc[5] * inv + b1.y, 0.f);
    o[6] = (_Float16)fmaxf(acc[6] * inv + b1.z, 0.f);
    o[7] = (_Float16)fmaxf(acc[7] * inv + b1.w, 0.f);
    reinterpret_cast<f16x8*>(Xo)[(size_t)v * 16 + s] = o;
  }
}

// ---------------- pooling (mean per graph) + BN ----------------

__global__ __launch_bounds__(512) void k_pool(const _Float16* __restrict__ X16,
                                              const int* __restrict__ batch,
                                              const float* __restrict__ bn,
                                              float* __restrict__ xg, int n) {
  __shared__ float4 part[16][32];
  int g = blockIdx.x;
  int s = threadIdx.x & 31;    // half4 col index
  int way = threadIdx.x >> 5;  // 0..15
  int lo = 0, hi = n;
  while (lo < hi) { int mid = (lo + hi) >> 1; if (batch[mid] < g) lo = mid + 1; else hi = mid; }
  int s0 = lo;
  lo = s0; hi = n;
  while (lo < hi) { int mid = (lo + hi) >> 1; if (batch[mid] < g + 1) lo = mid + 1; else hi = mid; }
  int e0 = lo;
  const half4_t* X4 = reinterpret_cast<const half4_t*>(X16);
  float4 acc = make_float4(0.f, 0.f, 0.f, 0.f);
  for (int i = s0 + way; i < e0; i += 16) {
    half4_t h = X4[(size_t)i * 32 + s];
    acc.x += (float)h[0]; acc.y += (float)h[1];
    acc.z += (float)h[2]; acc.w += (float)h[3];
  }
  part[way][s] = acc;
  __syncthreads();
  if (way == 0) {
    float4 t = part[0][s];
    #pragma unroll
    for (int w = 1; w < 16; ++w) {
      float4 u = part[w][s];
      t.x += u.x; t.y += u.y; t.z += u.z; t.w += u.w;
    }
    float invc = (e0 > s0) ? 1.f / (float)(e0 - s0) : 0.f;
    int c0 = s * 4;
    #pragma unroll
    for (int k = 0; k < 4; ++k) {
      float mean = ((const float*)&t)[k] * invc;
      int c = c0 + k;
      float gm = bn[c], bt = bn[128 + c], mu = bn[256 + c], vr = bn[384 + c];
      xg[g * 128 + c] = (mean - mu) * gm * rsqrtf(vr + EPSf) + bt;
    }
  }
}

// ---------------- heads ----------------

__global__ void k_heads(const float* __restrict__ xg, const float* __restrict__ gf,
                        const float* __restrict__ bn_t1, const float* __restrict__ bn_comb,
                        const float* __restrict__ fc1w, const float* __restrict__ fc1b,
                        const float* __restrict__ fc2w, const float* __restrict__ fc2b,
                        const float* __restrict__ fc3aw, const float* __restrict__ fc3ab,
                        const float* __restrict__ fc3bw, const float* __restrict__ fc3bb,
                        float* __restrict__ out) {
  int g = blockIdx.x;
  int lane = threadIdx.x;
  __shared__ float xs[128];
  __shared__ float x3[133];
  __shared__ float o2[2];
  xs[lane] = xg[g * 128 + lane];
  xs[lane + 64] = xg[g * 128 + 64 + lane];
  __syncthreads();
  const float* gfg = &gf[g * 8];
  float lev = gfg[7];
  float nx0 = gfg[5], nx1 = gfg[6], nx2 = gfg[7];
  float wf1 = gfg[2], wf2 = gfg[1];
  if (lane < 10) {
    float o = fc1b[lane];
    for (int k = 0; k < 128; ++k) o += xs[k] * fc1w[k * 10 + lane];
    o += lev * fc1w[128 * 10 + lane];
    o = fmaxf(o, 0.f);
    float gm = bn_t1[lane], bt = bn_t1[10 + lane], mu = bn_t1[20 + lane], vr = bn_t1[30 + lane];
    out[g * 10 + lane] = (o - mu) * gm * rsqrtf(vr + EPSf) + bt;
  }
  if (lane >= 10 && lane < 12) {
    int j = lane - 10;
    float o = fc2b[j];
    for (int k = 0; k < 128; ++k) o += xs[k] * fc2w[k * 2 + j];
    o += nx0 * fc2w[128 * 2 + j] + nx1 * fc2w[129 * 2 + j] + nx2 * fc2w[130 * 2 + j];
    o = fmaxf(o, 0.f);
    o2[j] = o;
    out[2560 + g * 2 + j] = o;
  }
  for (int k = lane; k < 133; k += 64) {
    float vsrc = (k < 128) ? xs[k]
               : (k == 128) ? wf1
               : (k == 129) ? wf2
               : (k == 130) ? nx0
               : (k == 131) ? nx1 : nx2;
    float gm = bn_comb[k], bt = bn_comb[133 + k], mu = bn_comb[266 + k], vr = bn_comb[399 + k];
    x3[k] = (vsrc - mu) * gm * rsqrtf(vr + EPSf) + bt;
  }
  __syncthreads();
  bool pred1 = o2[1] > o2[0];
  if (lane < 4) {
    float o = fc3ab[lane];
    for (int k = 0; k < 133; ++k) o += x3[k] * fc3aw[k * 4 + lane];
    out[3072 + g * 9 + lane] = pred1 ? 0.f : o;
  }
  if (lane >= 4 && lane < 9) {
    int j = lane - 4;
    float o = fc3bb[j];
    for (int k = 0; k < 133; ++k) o += x3[k] * fc3bw[k * 5 + j];
    out[3072 + g * 9 + 4 + j] = pred1 ? o : 0.f;
  }
}

// ---------------- launch ----------------

extern "C" void kernel_launch(void* const* d_in, const int* in_sizes, int n_in,
                              void* d_out, int out_size, void* d_ws, size_t ws_size,
                              hipStream_t stream) {
  const float* x      = (const float*)d_in[0];
  const int*   ei     = (const int*)d_in[1];
  const int*   batch  = (const int*)d_in[2];
  const float* gf     = (const float*)d_in[3];
  const float* gatW   = (const float*)d_in[5];
  const float* asrc   = (const float*)d_in[6];
  const float* adst   = (const float*)d_in[7];
  const float* gbias  = (const float*)d_in[8];
  const float* bn_emb = (const float*)d_in[9];
  const float* bn_t1  = (const float*)d_in[10];
  const float* bn_cb  = (const float*)d_in[11];
  const float* fc1w = (const float*)d_in[12]; const float* fc1b = (const float*)d_in[13];
  const float* fc2w = (const float*)d_in[14]; const float* fc2b = (const float*)d_in[15];
  const float* fc3aw = (const float*)d_in[16]; const float* fc3ab = (const float*)d_in[17];
  const float* fc3bw = (const float*)d_in[18]; const float* fc3bb = (const float*)d_in[19];
  float* out = (float*)d_out;

  char* p = (char*)d_ws;
  auto alloc = [&](size_t bytes) -> void* {
    void* r = (void*)p;
    p += (bytes + 255) & ~(size_t)255;
    return r;
  };
  _Float16* x16a = (_Float16*)alloc((size_t)Nn * 128 * 2);
  _Float16* x16b = (_Float16*)alloc((size_t)Nn * 128 * 2);
  _Float16* hbuf = (_Float16*)alloc((size_t)Nn * 128 * 2);
  _Float16* wt   = (_Float16*)alloc((size_t)3 * 16384 * 2);
  int2*  pairs = (int2*)alloc((size_t)Ee * 8);
  int*   csr  = (int*)alloc((size_t)Mm * 4);
  int*   rp   = (int*)alloc((size_t)(Nn + 1) * 4);
  int*   bcnt = (int*)alloc((size_t)NB * 4);
  int*   pairBase = (int*)alloc((size_t)NB * 4);
  int*   tailA    = (int*)alloc((size_t)NB * 4);
  int*   bbase    = (int*)alloc((size_t)NB * 4);
  float* es   = (float*)alloc((size_t)Nn * 4);
  float* ed   = (float*)alloc((size_t)Nn * 4);
  float* xg   = (float*)alloc((size_t)Gg * 128 * 4);
  if ((size_t)(p - (char*)d_ws) > ws_size) return;

  const int* srcp = ei;
  const int* dstp = ei + Ee;

  // conversions
  k_x2h<<<(Nn * 32 + 255) / 256, 256, 0, stream>>>(x, (half4_t*)x16a, Nn * 32);
  k_prepW<<<3, 256, 0, stream>>>(gatW, wt);

  // bucketed CSR build
  k_zero<<<(NB + 255) / 256, 256, 0, stream>>>(bcnt, NB);
  k_bcount<<<NEB, 256, 0, stream>>>(dstp, bcnt, Ee);
  k_bscan<<<1, 512, 0, stream>>>(bcnt, pairBase, tailA, bbase, rp);
  k_bin<<<NEB, 256, 0, stream>>>(srcp, dstp, tailA, pairs, Ee);
  k_place<<<NB, 256, 0, stream>>>(pairs, pairBase, bcnt, bbase, rp, csr);

  // 3 GAT layers (ping-pong fp16 feature buffers)
  _Float16* xin = x16a;
  _Float16* xout = x16b;
  int ngrid = (Nn + 127) / 128;
  for (int l = 0; l < 3; ++l) {
    k_gemm<<<ngrid, 256, 0, stream>>>(xin, wt + (size_t)l * 16384,
                                      asrc + l * 128, adst + l * 128,
                                      hbuf, es, ed, Nn);
    k_agg<<<(Nn + 3) / 4, 256, 0, stream>>>(hbuf, rp, csr, es, ed,
                                            gbias + l * 128, xout, Nn);
    _Float16* t = xin; xin = xout; xout = t;
  }

  k_pool<<<Gg, 512, 0, stream>>>(xin, batch, bn_emb, xg, Nn);

  k_heads<<<Gg, 64, 0, stream>>>(xg, gf, bn_t1, bn_cb,
                                 fc1w, fc1b, fc2w, fc2b, fc3aw, fc3ab, fc3bw, fc3bb, out);
}